// Round 1
// baseline (98.437 us; speedup 1.0000x reference)
//
#include <hip/hip_runtime.h>

// CantileverPINN: loss = mean((d4/dx4 w(x) - 1)^2), w = MLP 1->15->30->60->1 tanh.
// 4th-order Taylor-mode jet propagation, thread-per-point, fp32 VALU.

__device__ __forceinline__ float fast_tanh(float u) {
    float e = __expf(2.0f * u);
    return 1.0f - 2.0f / (e + 1.0f);   // handles e=inf -> 1, e=0 -> -1
}

// tanh derivative factors: t, s=phi', p2=phi'', p3=phi''', p4=phi''''
struct TanhD {
    float t, s, p2, p3, p4;
};

__device__ __forceinline__ TanhD tanh_derivs(float u0) {
    TanhD d;
    float t = fast_tanh(u0);
    float s = fmaf(-t, t, 1.0f);
    float ts = t * s;
    float t2 = t * t;
    d.t = t;
    d.s = s;
    d.p2 = -2.0f * ts;
    d.p3 = s * fmaf(4.0f, t2, -2.0f * s);                 // s(4t^2 - 2s)
    d.p4 = 8.0f * ts * fmaf(-1.0f, t2, 2.0f * s);         // 8ts(2s - t^2)
    return d;
}

// full jet composition f = tanh(u), derivatives up to 4th order
__device__ __forceinline__ void tanh_jet(const float u[5], float f[5]) {
    TanhD d = tanh_derivs(u[0]);
    float u1 = u[1], u2 = u[2], u3 = u[3], u4 = u[4];
    float u1sq = u1 * u1;
    f[0] = d.t;
    f[1] = d.s * u1;
    f[2] = fmaf(d.p2, u1sq, d.s * u2);
    f[3] = fmaf(d.p3, u1sq * u1, fmaf(3.0f * d.p2, u1 * u2, d.s * u3));
    f[4] = fmaf(d.p4, u1sq * u1sq,
           fmaf(6.0f * d.p3, u1sq * u2,
           fmaf(3.0f * d.p2, u2 * u2,
           fmaf(4.0f * d.p2, u1 * u3, d.s * u4))));
}

// only the 4th derivative component (for the last hidden layer, fused with W4)
__device__ __forceinline__ float tanh_jet_d4(const float u[5]) {
    TanhD d = tanh_derivs(u[0]);
    float u1 = u[1], u2 = u[2], u3 = u[3], u4 = u[4];
    float u1sq = u1 * u1;
    return fmaf(d.p4, u1sq * u1sq,
           fmaf(6.0f * d.p3, u1sq * u2,
           fmaf(3.0f * d.p2, u2 * u2,
           fmaf(4.0f * d.p2, u1 * u3, d.s * u4))));
}

__global__ __launch_bounds__(256, 2)
void pinn_jet_kernel(const float* __restrict__ x,
                     const float* __restrict__ W1, const float* __restrict__ b1,
                     const float* __restrict__ W2, const float* __restrict__ b2,
                     const float* __restrict__ W3, const float* __restrict__ b3,
                     const float* __restrict__ W4,
                     float* __restrict__ partials, int n) {
    // weights in LDS: W2 row-major [15][30] (i-outer scatter), W3 transposed
    // [60][32] padded rows (j-outer gather with float4 reads).
    __shared__ float sW1[15], sB1[15];
    __shared__ float sW2[15 * 30];
    __shared__ float sB2[30];
    __shared__ float sW3T[60 * 32];
    __shared__ float sB3[60], sW4[60];
    __shared__ float wsum[4];

    const int t = threadIdx.x;
    for (int idx = t; idx < 450; idx += 256) sW2[idx] = W2[idx];
    for (int idx = t; idx < 1800; idx += 256) {
        int j = idx / 30, i = idx % 30;
        sW3T[j * 32 + i] = W3[i * 60 + j];
    }
    if (t < 15) { sW1[t] = W1[t]; sB1[t] = b1[t]; }
    if (t < 30) { sB2[t] = b2[t]; }
    if (t < 60) { sB3[t] = b3[t]; sW4[t] = W4[t]; }
    __syncthreads();

    const int gid = blockIdx.x * 256 + t;
    const float xi = (gid < n) ? x[gid] : 0.0f;

    // ---- Layer 1 + Layer 2 accumulate (i-outer: peak regs = z2[150] + jet[5]) ----
    float z2[30][5];
    #pragma unroll
    for (int j = 0; j < 30; ++j) {
        z2[j][0] = sB2[j];
        z2[j][1] = 0.0f; z2[j][2] = 0.0f; z2[j][3] = 0.0f; z2[j][4] = 0.0f;
    }
    #pragma unroll
    for (int i = 0; i < 15; ++i) {
        // h1 neuron i jet: u = w*x + b, u1 = w, u2..u4 = 0
        const float w = sW1[i];
        TanhD d = tanh_derivs(fmaf(w, xi, sB1[i]));
        const float w2 = w * w;
        float g[5];
        g[0] = d.t;
        g[1] = d.s * w;
        g[2] = d.p2 * w2;
        g[3] = d.p3 * w2 * w;
        g[4] = d.p4 * w2 * w2;
        #pragma unroll
        for (int j = 0; j < 30; ++j) {
            const float wij = sW2[i * 30 + j];
            #pragma unroll
            for (int k = 0; k < 5; ++k) z2[j][k] = fmaf(wij, g[k], z2[j][k]);
        }
    }
    // finalize layer 2: h2 = tanh_jet(z2), in place
    float h2[30][5];
    #pragma unroll
    for (int j = 0; j < 30; ++j) tanh_jet(z2[j], h2[j]);

    // ---- Layer 3 (j-outer, rolled) fused with layer 4 (only d4 needed) ----
    float acc4 = 0.0f;
    for (int j = 0; j < 60; ++j) {
        float z[5];
        z[0] = sB3[j]; z[1] = 0.0f; z[2] = 0.0f; z[3] = 0.0f; z[4] = 0.0f;
        const float* row = &sW3T[j * 32];
        #pragma unroll
        for (int q = 0; q < 7; ++q) {
            const float4 wv = *(const float4*)&row[q * 4];
            const int i = q * 4;
            #pragma unroll
            for (int k = 0; k < 5; ++k) z[k] = fmaf(wv.x, h2[i + 0][k], z[k]);
            #pragma unroll
            for (int k = 0; k < 5; ++k) z[k] = fmaf(wv.y, h2[i + 1][k], z[k]);
            #pragma unroll
            for (int k = 0; k < 5; ++k) z[k] = fmaf(wv.z, h2[i + 2][k], z[k]);
            #pragma unroll
            for (int k = 0; k < 5; ++k) z[k] = fmaf(wv.w, h2[i + 3][k], z[k]);
        }
        {
            const float2 wv = *(const float2*)&row[28];
            #pragma unroll
            for (int k = 0; k < 5; ++k) z[k] = fmaf(wv.x, h2[28][k], z[k]);
            #pragma unroll
            for (int k = 0; k < 5; ++k) z[k] = fmaf(wv.y, h2[29][k], z[k]);
        }
        acc4 = fmaf(sW4[j], tanh_jet_d4(z), acc4);
    }

    // residual^2; P/(E*I) = 1
    const float r = acc4 - 1.0f;
    float val = (gid < n) ? r * r : 0.0f;

    // block reduction -> partials[blockIdx.x]
    #pragma unroll
    for (int off = 32; off > 0; off >>= 1) val += __shfl_down(val, off, 64);
    const int wid = t >> 6;
    if ((t & 63) == 0) wsum[wid] = val;
    __syncthreads();
    if (t == 0) partials[blockIdx.x] = wsum[0] + wsum[1] + wsum[2] + wsum[3];
}

__global__ __launch_bounds__(256)
void pinn_reduce_kernel(const float* __restrict__ partials, int nblocks,
                        float* __restrict__ out, float inv_n) {
    __shared__ float ws[4];
    const int t = threadIdx.x;
    float v = 0.0f;
    for (int i = t; i < nblocks; i += 256) v += partials[i];
    #pragma unroll
    for (int off = 32; off > 0; off >>= 1) v += __shfl_down(v, off, 64);
    if ((t & 63) == 0) ws[t >> 6] = v;
    __syncthreads();
    if (t == 0) out[0] = (ws[0] + ws[1] + ws[2] + ws[3]) * inv_n;
}

extern "C" void kernel_launch(void* const* d_in, const int* in_sizes, int n_in,
                              void* d_out, int out_size, void* d_ws, size_t ws_size,
                              hipStream_t stream) {
    const float* x  = (const float*)d_in[0];
    const float* W1 = (const float*)d_in[1];
    const float* b1 = (const float*)d_in[2];
    const float* W2 = (const float*)d_in[3];
    const float* b2 = (const float*)d_in[4];
    const float* W3 = (const float*)d_in[5];
    const float* b3 = (const float*)d_in[6];
    const float* W4 = (const float*)d_in[7];
    // d_in[8] = b4: constant offset on w(x); vanishes under d^4/dx^4.

    const int n = in_sizes[0];
    const int nblocks = (n + 255) / 256;
    float* partials = (float*)d_ws;

    pinn_jet_kernel<<<nblocks, 256, 0, stream>>>(x, W1, b1, W2, b2, W3, b3, W4,
                                                 partials, n);
    pinn_reduce_kernel<<<1, 256, 0, stream>>>(partials, nblocks, (float*)d_out,
                                              1.0f / (float)n);
}